// Round 5
// baseline (1383.181 us; speedup 1.0000x reference)
//
#include <hip/hip_runtime.h>
#include <cstdint>

// ============================================================================
// RBM_BB block Gibbs, bit-exact (recipe frozen, R3/R5/R6/R7-verified):
//   keys   : partitionable threefry; fold-like split key_i = threefry(parent,0,i)
//   bits   : w0 ^ w1 of threefry(key, 0, flat_index); u = (bits>>9|1.0f)-1
//   sample : u < p
//   sigmoid: 1/(1+cephes_expf(-pre)), noFMA Horner, trailing max(res,x)
//   dot    : f32 sequential ascending-k, folded at kc=320 panel boundaries
// R12: 128x128 tile, 8m x 8n per-thread (1.0 LDS-B/FMA).
// R13: __launch_bounds__(256,3) — avoids allocator spill.
// R15: v_pk_fma_f32 via inline asm (op_sel broadcast). Non-SAMPLE GEMM hit
//      ~190 effective TF (~46 us for 8.6 GF). SAMPLE instantiation REGRESSED
//      (VGPR 68: epilogue pressure starved the main loop; LDS latency exposed,
//      VALUBusy 58%).
// R16: de-fuse the v-step. All hot GEMMs now run the proven non-SAMPLE pk
//      instantiation; v pre-activations go to out_v in place, then
//      sample_inplace applies bias+sigmoid+threefry elementwise (flat = idx,
//      identical recipe; preact f32 round-trip is exact). Fused-SAMPLE
//      variant retained only for the no-workspace fallback.
// ============================================================================

typedef float f32x2 __attribute__((ext_vector_type(2)));

// acc.{lo,hi} += a2.lo * b2.{lo,hi}  (src0 lo broadcast)
#define PK_FMA_LO(acc, a2, b2) \
  asm("v_pk_fma_f32 %0, %1, %2, %0 op_sel:[0,0,0] op_sel_hi:[0,1,1]" \
      : "+v"(acc) : "v"(a2), "v"(b2))
// acc.{lo,hi} += a2.hi * b2.{lo,hi}  (src0 hi broadcast)
#define PK_FMA_HI(acc, a2, b2) \
  asm("v_pk_fma_f32 %0, %1, %2, %0 op_sel:[1,0,0] op_sel_hi:[1,1,1]" \
      : "+v"(acc) : "v"(a2), "v"(b2))

__host__ __device__ __forceinline__ uint32_t tf_rot(uint32_t x, int r) {
#ifdef __HIP_DEVICE_COMPILE__
  return __builtin_amdgcn_alignbit(x, x, (uint32_t)(32 - r));  // rotl(x,r)
#else
  return (x << r) | (x >> (32 - r));
#endif
}

__host__ __device__ __forceinline__ void threefry2x32(
    uint32_t k0, uint32_t k1, uint32_t x0, uint32_t x1,
    uint32_t &o0, uint32_t &o1) {
  const uint32_t ks2 = k0 ^ k1 ^ 0x1BD11BDAu;
  x0 += k0; x1 += k1;
#define TF_R(r) { x0 += x1; x1 = tf_rot(x1, r); x1 ^= x0; }
  TF_R(13) TF_R(15) TF_R(26) TF_R(6)
  x0 += k1; x1 += ks2 + 1u;
  TF_R(17) TF_R(29) TF_R(16) TF_R(24)
  x0 += ks2; x1 += k0 + 2u;
  TF_R(13) TF_R(15) TF_R(26) TF_R(6)
  x0 += k0; x1 += k1 + 3u;
  TF_R(17) TF_R(29) TF_R(16) TF_R(24)
  x0 += k1; x1 += ks2 + 4u;
  TF_R(13) TF_R(15) TF_R(26) TF_R(6)
  x0 += ks2; x1 += k0 + 5u;
#undef TF_R
  o0 = x0; o1 = x1;
}

// Cephes expf, noFMA (verified in-chain).
__device__ __forceinline__ float cephes_expf(float xin) {
  float xc = fminf(xin, 88.3762626647950f);
  xc = fmaxf(xc, -88.3762626647949f);
  float fx = floorf(xc * 1.44269504088896341f + 0.5f);
  float tmp = 0.693359375f * fx;
  float z2  = -2.12194440e-4f * fx;
  float x = xc - tmp;
  x = x - z2;
  float z = x * x;
  float y = 1.9875691500E-4f * x + 1.3981999507E-3f;
  y = y * x + 8.3334519073E-3f;
  y = y * x + 4.1665795894E-2f;
  y = y * x + 1.6666665459E-1f;
  y = y * x + 5.0000001201E-1f;
  y = y * z + x;
  y = 1.0f + y;
  int n = (int)fx;
  float p2n = __uint_as_float((uint32_t)(n + 127) << 23);
  return fmaxf(y * p2n, xin);
}

// flat-index form (preact already includes nothing; bias added here)
__device__ __forceinline__ float sample_flat(
    float tot, float bias, uint32_t flat, uint32_t k0, uint32_t k1) {
  float pre = tot + bias;
  float p   = 1.0f / (1.0f + cephes_expf(-pre));
  uint32_t w0, w1;
  threefry2x32(k0, k1, 0u, flat, w0, w1);
  uint32_t bits = w0 ^ w1;
  float u = __uint_as_float((bits >> 9) | 0x3f800000u) - 1.0f;
  return (u < p) ? 1.0f : 0.0f;
}

__device__ __forceinline__ float sample_val(
    float tot, float bias, long b, int ng, int N_total,
    uint32_t k0, uint32_t k1) {
  return sample_flat(tot, bias, (uint32_t)(b * N_total + ng), k0, k1);
}

// async global->LDS, 16B per lane; LDS dest = uniform base + lane*16.
__device__ __forceinline__ void gl2lds16(const float* g, float* l) {
  __builtin_amdgcn_global_load_lds(
      (const __attribute__((address_space(1))) void*)g,
      (__attribute__((address_space(3))) void*)l, 16, 0, 0);
}

// ----------------------------------------------------------------------------
// Main GEMM, 128x128 tile, BK=32, 256 threads, 8m x 8n per thread.
// A [Mtot,lda] row-major (k-contig); Bkm [K, ldb] k-major (n-contig rows).
// Thread (tx=t&15, ty=t>>4): rows m = ty+16*i (i=0..7), cols n = 4*tx+64*jq+e.
// Accumulators: f32x2 pairs of ADJACENT columns, fed by v_pk_fma_f32 with
// op_sel src0 broadcast; each column keeps an independent IEEE-fma chain.
// SAMPLE=0 (hot path): writes raw f32 partial/preact to
//   outp[b*N_total + j0 + n0]; split-K z offsets by z*Mtot*N_total.
// SAMPLE=1 (fallback only): fused sigmoid+threefry epilogue.
// Per-output chain: k = 32*tk + 4*c + cc, c outer asc, cc inner asc (exact).
// ----------------------------------------------------------------------------
template <bool SAMPLE>
__global__ __launch_bounds__(256, 3) void gemm_tile128(
    const float* __restrict__ A,     // [Mtot, lda]
    const float* __restrict__ Bkm,   // [K, ldb] k-major
    const float* __restrict__ bias,  // [N_total] (SAMPLE only)
    float* __restrict__ out,
    int lda, int ldb, int N_total, int K, int Mtot,
    uint32_t k0, uint32_t k1)
{
  __shared__ float As[128 * 32];    // [m][k] unpadded (lds-dma linear layout)
  __shared__ float Bs[32 * 128];    // [k][n] unpadded
  const int t  = threadIdx.x;
  const int tx = t & 15;
  const int ty = t >> 4;
  const int w  = t >> 6;            // wave id
  const int bm = blockIdx.x;
  const int j0 = blockIdx.y << 7;

  int kb, ke;
  float* outp = out;
  if (SAMPLE) { kb = 0; ke = K; }
  else {
    const int z = blockIdx.z;
    kb = z * 320;
    ke = min(K, kb + 320);
    outp = out + (size_t)z * Mtot * N_total;
  }

  // cur[i][q]: q=0,1 -> cols 4tx+{0,1},{2,3}; q=2,3 -> cols 4tx+64+{0,1},{2,3}
  f32x2 cur[8][4];
#pragma unroll
  for (int i = 0; i < 8; ++i)
#pragma unroll
    for (int q = 0; q < 4; ++q) cur[i][q] = f32x2{0.0f, 0.0f};

  const long arow = (long)bm * 128 * lda;
  const int nt = (ke - kb) >> 5;    // k-tiles in this block's range

  // A tile: 1024 f4 slots, 4 rounds; slot = r*256+t; m = 32r + (t>>3), c = t&7.
  // B tile: 1024 f4 slots, 4 rounds; slot = r*256+t; kk = 8r + (t>>5), nc = t&31.
  const long aStepR = (long)32 * lda;   // A rows advance per round
  const long bStepR = (long)8  * ldb;   // B rows advance per round
  const float* aG = A + arow + (long)(t >> 3) * lda + 4 * (t & 7) + kb;
  const float* bG = Bkm + (long)(t >> 5) * ldb + j0 + 4 * (t & 31) + (long)kb * ldb;
  const long bStepT = (long)32 * ldb;   // B advance per k-tile

  const float* aP = As + ty * 32;
  const float* bP = Bs + 4 * tx;

  for (int tk = 0; tk < nt; ++tk) {
    __syncthreads();   // protect LDS reuse (prev tile's reads done)
#pragma unroll
    for (int r = 0; r < 4; ++r)
      gl2lds16(aG + r * aStepR, As + (r * 256 + w * 64) * 4);
#pragma unroll
    for (int r = 0; r < 4; ++r)
      gl2lds16(bG + r * bStepR, Bs + (r * 256 + w * 64) * 4);
    __syncthreads();   // vmcnt(0) drain: staged data visible

    // ---- compute: k ascending 4c+cc per output; B regs live across i ----
#pragma unroll
    for (int c = 0; c < 8; ++c) {
      float4 b0[4], b1[4];
#pragma unroll
      for (int cc = 0; cc < 4; ++cc) {
        const float* brow = bP + (4 * c + cc) * 128;
        b0[cc] = *(const float4*)(brow);
        b1[cc] = *(const float4*)(brow + 64);
      }
#pragma unroll
      for (int i = 0; i < 8; ++i) {
        const float4 av = *(const float4*)(aP + i * 16 * 32 + 4 * c);
        const f32x2* ap = (const f32x2*)&av;      // ap[0]={k0,k1}, ap[1]={k2,k3}
        // cc = 0: a = av.x (ap[0].lo)
        { const f32x2* q0 = (const f32x2*)&b0[0];
          const f32x2* q1 = (const f32x2*)&b1[0];
          PK_FMA_LO(cur[i][0], ap[0], q0[0]);
          PK_FMA_LO(cur[i][1], ap[0], q0[1]);
          PK_FMA_LO(cur[i][2], ap[0], q1[0]);
          PK_FMA_LO(cur[i][3], ap[0], q1[1]); }
        // cc = 1: a = av.y (ap[0].hi)
        { const f32x2* q0 = (const f32x2*)&b0[1];
          const f32x2* q1 = (const f32x2*)&b1[1];
          PK_FMA_HI(cur[i][0], ap[0], q0[0]);
          PK_FMA_HI(cur[i][1], ap[0], q0[1]);
          PK_FMA_HI(cur[i][2], ap[0], q1[0]);
          PK_FMA_HI(cur[i][3], ap[0], q1[1]); }
        // cc = 2: a = av.z (ap[1].lo)
        { const f32x2* q0 = (const f32x2*)&b0[2];
          const f32x2* q1 = (const f32x2*)&b1[2];
          PK_FMA_LO(cur[i][0], ap[1], q0[0]);
          PK_FMA_LO(cur[i][1], ap[1], q0[1]);
          PK_FMA_LO(cur[i][2], ap[1], q1[0]);
          PK_FMA_LO(cur[i][3], ap[1], q1[1]); }
        // cc = 3: a = av.w (ap[1].hi)
        { const f32x2* q0 = (const f32x2*)&b0[3];
          const f32x2* q1 = (const f32x2*)&b1[3];
          PK_FMA_HI(cur[i][0], ap[1], q0[0]);
          PK_FMA_HI(cur[i][1], ap[1], q0[1]);
          PK_FMA_HI(cur[i][2], ap[1], q1[0]);
          PK_FMA_HI(cur[i][3], ap[1], q1[1]); }
      }
    }
    aG += 32;
    bG += bStepT;
  }

  // ---- epilogue: per (i,jq), 4 consecutive cols -> one float4 store ----
#pragma unroll
  for (int i = 0; i < 8; ++i) {
    const int m = ty + 16 * i;
    const long b = (long)bm * 128 + m;
#pragma unroll
    for (int jq = 0; jq < 2; ++jq) {
      const int n0 = 4 * tx + 64 * jq;
      const f32x2 e01 = cur[i][2 * jq + 0];
      const f32x2 e23 = cur[i][2 * jq + 1];
      float4 o;
      if (SAMPLE) {
        const int ng = j0 + n0;
        o.x = sample_val(e01.x, bias[ng],     b, ng,     N_total, k0, k1);
        o.y = sample_val(e01.y, bias[ng + 1], b, ng + 1, N_total, k0, k1);
        o.z = sample_val(e23.x, bias[ng + 2], b, ng + 2, N_total, k0, k1);
        o.w = sample_val(e23.y, bias[ng + 3], b, ng + 3, N_total, k0, k1);
        *(float4*)(outp + b * N_total + ng) = o;
      } else {
        o.x = e01.x; o.y = e01.y; o.z = e23.x; o.w = e23.y;
        *(float4*)(outp + b * N_total + j0 + n0) = o;   // raw preact/partial
      }
    }
  }
}

// ----------------------------------------------------------------------------
// In-place elementwise sampler for the v-step: vbuf holds f32 preacts
// (W^T h), becomes binary samples. flat = linear idx (== b*1024 + ng).
// ----------------------------------------------------------------------------
__global__ __launch_bounds__(256) void sample_inplace(
    float* __restrict__ vbuf,            // [B*1024]
    const float* __restrict__ bias,      // [1024]
    uint32_t k0, uint32_t k1)
{
  const long i4 = (long)blockIdx.x * 256 + threadIdx.x;  // float4 index
  float4 pv = ((const float4*)vbuf)[i4];
  const uint32_t n0 = (uint32_t)(i4 << 2);
  const int bg = (int)(n0 & 1023);
  const float4 bq = *(const float4*)(bias + bg);
  float4 o;
  o.x = sample_flat(pv.x, bq.x, n0 + 0u, k0, k1);
  o.y = sample_flat(pv.y, bq.y, n0 + 1u, k0, k1);
  o.z = sample_flat(pv.z, bq.z, n0 + 2u, k0, k1);
  o.w = sample_flat(pv.w, bq.w, n0 + 3u, k0, k1);
  ((float4*)vbuf)[i4] = o;
}

// ----------------------------------------------------------------------------
// Fallback (no-workspace path only): 64x128 kernel, SAMPLE over full K with
// in-kernel panel folds (tiles_per_panel=10). Not used when split-K workspace
// is available.
// ----------------------------------------------------------------------------
__global__ __launch_bounds__(256, 5) void gemm_fb(
    const float* __restrict__ A,     // [Mtot, lda]
    const float* __restrict__ Bkm,   // [K, ldb] k-major
    const float* __restrict__ bias,  // [N_total]
    float* __restrict__ out,
    int lda, int ldb, int N_total, int K, int tiles_per_panel, int Mtot,
    uint32_t k0, uint32_t k1)
{
  __shared__ float As[64 * 32];
  __shared__ float Bs[32 * 128];
  const int t  = threadIdx.x;
  const int tx = t & 15;
  const int ty = t >> 4;
  const int w  = t >> 6;
  const int bm = blockIdx.x;
  const int j0 = blockIdx.y << 7;

  const int kb = 0, ke = K;

  float cur[4][8];
  float tot[4][8];
#pragma unroll
  for (int i = 0; i < 4; ++i)
#pragma unroll
    for (int j = 0; j < 8; ++j) { cur[i][j] = 0.0f; tot[i][j] = 0.0f; }

  const long arow = (long)bm * 64 * lda;
  const int t0 = kb >> 5, t1 = ke >> 5;

  const float* aP = As + ty * 32;
  const float* bP = Bs + 4 * tx;

  for (int tki = t0; tki < t1; ++tki) {
    const int kc = tki << 5;
    __syncthreads();
#pragma unroll
    for (int r = 0; r < 2; ++r) {
      int slot = r * 256 + t;
      int m = slot >> 3, c = slot & 7;
      gl2lds16(A + arow + (long)m * lda + kc + 4 * c,
               As + (r * 256 + w * 64) * 4);
    }
#pragma unroll
    for (int r = 0; r < 4; ++r) {
      int slot = r * 256 + t;
      int kk = slot >> 5, nc = slot & 31;
      gl2lds16(Bkm + (long)(kc + kk) * ldb + j0 + 4 * nc,
               Bs + (r * 256 + w * 64) * 4);
    }
    __syncthreads();

#pragma unroll
    for (int c = 0; c < 8; ++c) {
      float4 av[4];
#pragma unroll
      for (int i = 0; i < 4; ++i)
        av[i] = *(const float4*)(aP + i * 16 * 32 + 4 * c);
#pragma unroll
      for (int cc = 0; cc < 4; ++cc) {
        const float* brow = bP + (4 * c + cc) * 128;
        float4 b0 = *(const float4*)(brow);
        float4 b1 = *(const float4*)(brow + 64);
#pragma unroll
        for (int i = 0; i < 4; ++i) {
          const float a = ((const float*)&av[i])[cc];
          cur[i][0] = __fmaf_rn(a, b0.x, cur[i][0]);
          cur[i][1] = __fmaf_rn(a, b0.y, cur[i][1]);
          cur[i][2] = __fmaf_rn(a, b0.z, cur[i][2]);
          cur[i][3] = __fmaf_rn(a, b0.w, cur[i][3]);
          cur[i][4] = __fmaf_rn(a, b1.x, cur[i][4]);
          cur[i][5] = __fmaf_rn(a, b1.y, cur[i][5]);
          cur[i][6] = __fmaf_rn(a, b1.z, cur[i][6]);
          cur[i][7] = __fmaf_rn(a, b1.w, cur[i][7]);
        }
      }
    }

    if (((tki - t0 + 1) % tiles_per_panel == 0) || (tki == t1 - 1)) {
#pragma unroll
      for (int i = 0; i < 4; ++i)
#pragma unroll
        for (int j = 0; j < 8; ++j) { tot[i][j] += cur[i][j]; cur[i][j] = 0.0f; }
    }
  }

#pragma unroll
  for (int i = 0; i < 4; ++i) {
    const int m = ty + 16 * i;
    const long b = (long)bm * 64 + m;
#pragma unroll
    for (int jq = 0; jq < 2; ++jq) {
      const int n0 = 4 * tx + 64 * jq;
      const int ng = j0 + n0;
      float4 o;
      o.x = sample_val(tot[i][4 * jq + 0], bias[ng],     b, ng,     N_total, k0, k1);
      o.y = sample_val(tot[i][4 * jq + 1], bias[ng + 1], b, ng + 1, N_total, k0, k1);
      o.z = sample_val(tot[i][4 * jq + 2], bias[ng + 2], b, ng + 2, N_total, k0, k1);
      o.w = sample_val(tot[i][4 * jq + 3], bias[ng + 3], b, ng + 3, N_total, k0, k1);
      *(float4*)(out + b * N_total + ng) = o;
    }
  }
}

// Fold 4 panel partials in exact order, then bias+sigmoid+sample.
__global__ __launch_bounds__(256) void combine_sample(
    const float* __restrict__ partials,  // [4][Mtot*128]
    const float* __restrict__ bias,      // [128]
    float* __restrict__ out,             // [Mtot*128] binary f32
    int Mtot, uint32_t k0, uint32_t k1)
{
  const long idx = (long)blockIdx.x * 256 + threadIdx.x;
  const long S = (long)Mtot * 128;
  float p0 = partials[idx];
  float p1 = partials[S + idx];
  float p2 = partials[2 * S + idx];
  float p3 = partials[3 * S + idx];
  float tot = ((p0 + p1) + p2) + p3;          // Eigen fold order, exact
  float pre = tot + bias[(int)(idx & 127)];
  float p   = 1.0f / (1.0f + cephes_expf(-pre));
  uint32_t w0, w1;
  threefry2x32(k0, k1, 0u, (uint32_t)idx, w0, w1);
  uint32_t bits = w0 ^ w1;
  float u = __uint_as_float((bits >> 9) | 0x3f800000u) - 1.0f;
  out[idx] = (u < p) ? 1.0f : 0.0f;
}

__global__ void transpose_W(const float* __restrict__ W, float* __restrict__ Wt) {
  __shared__ float tile[32][33];
  int bx = blockIdx.x, by = blockIdx.y;
  int x = threadIdx.x, y = threadIdx.y;
  tile[y][x] = W[(by * 32 + y) * 1024 + bx * 32 + x];
  __syncthreads();
  Wt[(bx * 32 + y) * 128 + by * 32 + x] = tile[x][y];
}

extern "C" void kernel_launch(void* const* d_in, const int* in_sizes, int n_in,
                              void* d_out, int out_size, void* d_ws, size_t ws_size,
                              hipStream_t stream) {
  const float* v0 = (const float*)d_in[0];   // [B,1024]
  const float* W  = (const float*)d_in[1];   // [128,1024]
  const float* bb = (const float*)d_in[2];   // [1024]
  const float* cb = (const float*)d_in[3];   // [128]
  const int B = in_sizes[0] / 1024;          // 32768

  float* out    = (float*)d_out;
  float* out_v  = out;                        // v_given_h   [B,1024]
  float* out_h1 = out + (size_t)B * 1024;     // h_given_v   [B,128]
  float* out_h2 = out_h1 + (size_t)B * 128;   // h_given_v_0 [B,128]

  float* Wt       = (float*)d_ws;                       // [1024,128] k-major for h-GEMM
  float* h_ws     = Wt + 1024 * 128;                    // [B,128]
  float* partials = h_ws + (size_t)B * 128;             // [4][B,128]
  const size_t need = (size_t)(1024 * 128 + (size_t)B * 128 * 5) * 4;
  const bool use_split = ws_size >= need;

  // partitionable keys: seed 42, fold-like split
  uint32_t kt[5][2], kv[5][2], kh[5][2];
  for (uint32_t i = 0; i < 5; ++i) threefry2x32(0u, 42u, 0u, i, kt[i][0], kt[i][1]);
  for (int t = 1; t <= 4; ++t) {
    threefry2x32(kt[t][0], kt[t][1], 0u, 0u, kv[t][0], kv[t][1]);
    threefry2x32(kt[t][0], kt[t][1], 0u, 1u, kh[t][0], kh[t][1]);
  }

  transpose_W<<<dim3(32, 4), dim3(32, 32), 0, stream>>>(W, Wt);

  const int MB = B / 128;    // 256 row-blocks (128-row tiles)

  // h-step: hdst = bernoulli(key, sigmoid(W vin + c)); Bkm = Wt (ldb=128)
  auto h_step = [&](const float* vin, float* hdst, uint32_t hk0, uint32_t hk1) {
    if (use_split) {
      gemm_tile128<false><<<dim3(MB, 1, 4), 256, 0, stream>>>(
          vin, Wt, nullptr, partials, 1024, 128, 128, 1024, B, 0u, 0u);
      combine_sample<<<dim3(B * 128 / 256), 256, 0, stream>>>(
          partials, cb, hdst, B, hk0, hk1);
    } else {
      gemm_fb<<<dim3(B / 64, 1, 1), 256, 0, stream>>>(
          vin, Wt, cb, hdst, 1024, 128, 128, 1024, 10, B, hk0, hk1);
    }
  };

  // h0 = bernoulli(kt[0], sigmoid(W v0 + c))
  h_step(v0, out_h2, kt[0][0], kt[0][1]);

  const float* h = out_h2;
  for (int t = 1; t <= 4; ++t) {
    // v_t = bernoulli(kv[t], sigmoid(W^T h + b)) — K=128 (<320, single panel)
    if (use_split) {
      // preacts into out_v (non-SAMPLE hot instantiation), then in-place sample
      gemm_tile128<false><<<dim3(MB, 8, 1), 256, 0, stream>>>(
          h, W, nullptr, out_v, 128, 1024, 1024, 128, B, 0u, 0u);
      sample_inplace<<<dim3(B), 256, 0, stream>>>(   // B*1024/4/256 = B blocks
          out_v, bb, kv[t][0], kv[t][1]);
    } else {
      gemm_tile128<true><<<dim3(MB, 8, 1), 256, 0, stream>>>(
          h, W, bb, out_v, 128, 1024, 1024, 128, B, kv[t][0], kv[t][1]);
    }
    // h_t = bernoulli(kh[t], sigmoid(W v_t + c))
    float* hdst = (t == 4) ? out_h1 : h_ws;
    h_step(out_v, hdst, kh[t][0], kh[t][1]);
    h = hdst;
  }
}